// Round 9
// baseline (228.483 us; speedup 1.0000x reference)
//
#include <hip/hip_runtime.h>
#include <hip/hip_bf16.h>

typedef long long i64;
typedef unsigned int uint;
using u16 = unsigned short;
using f32x4  = __attribute__((ext_vector_type(4))) float;
using bf16x8 = __attribute__((ext_vector_type(8))) short;
using u32x4  = __attribute__((ext_vector_type(4))) uint;
using u16x4  = __attribute__((ext_vector_type(4))) u16;

// 0.125 (attention scaling) * log2(e): folded into q bf16 copy so softmax
// uses exp2 directly. Softmax is invariant to the base change.
#define QSCALE 0.18033688011112042f

__device__ __forceinline__ u16 f2b(float x) {   // f32 -> bf16 RNE
    uint u = __float_as_uint(x);
    return (u16)((u + 0x7FFFu + ((u >> 16) & 1u)) >> 16);
}
__device__ __forceinline__ uint cvt_pk_bf16(float lo, float hi) {
    uint r;
    asm("v_cvt_pk_bf16_f32 %0, %1, %2" : "=v"(r) : "v"(lo), "v"(hi));
    return r;
}

// ---------------------------------------------------------------------------
// conv_pad: f32 [M_valid x K_valid] (row stride s_row) -> bf16 [Mpad][Kpad],
// zero-padded. Kpad = 1<<kshift.
// ---------------------------------------------------------------------------
__global__ __launch_bounds__(256) void conv_pad(
    const float* __restrict__ src, u16* __restrict__ dst,
    int M_valid, int K_valid, int kshift, int s_row)
{
    i64 i = (i64)blockIdx.x * 256 + threadIdx.x;   // over Mpad*Kpad/4
    int m = (int)(i >> (kshift - 2));
    int k = ((int)(i & ((1 << (kshift - 2)) - 1))) << 2;
    u16x4 hv;
    #pragma unroll
    for (int j = 0; j < 4; ++j) {
        int kk = k + j;
        float x = (m < M_valid && kk < K_valid) ? src[(i64)m * s_row + kk] : 0.f;
        hv[j] = f2b(x);
    }
    *(u16x4*)(dst + ((i64)m << kshift) + k) = hv;
}

// ---------------------------------------------------------------------------
// conv_wout_perm: dst[n][kp] = bf16(w_out[n][(kp&63)*16 + (kp>>6)])
// ---------------------------------------------------------------------------
__global__ __launch_bounds__(256) void conv_wout_perm(
    const float* __restrict__ w, u16* __restrict__ dst)
{
    int i = blockIdx.x * 256 + threadIdx.x;        // over 1024*1024/4
    int n = i >> 8, kp4 = (i & 255) << 2;
    u16x4 hv;
    #pragma unroll
    for (int j = 0; j < 4; ++j) {
        int kp = kp4 + j;
        hv[j] = f2b(w[((i64)n << 10) + ((kp & 63) << 4) + (kp >> 6)]);
    }
    *(u16x4*)(dst + ((i64)n << 10) + kp4) = hv;
}

// ---------------------------------------------------------------------------
// build_kvA: A-panel for the kv-GEMM, transposed to l-contiguous bf16.
// rows 0..1023: A[d][l] = X[l][b][d]; rows 1024..1535: A[1024+c][l]=qp[(l4+b)c]
// ---------------------------------------------------------------------------
__global__ __launch_bounds__(256) void build_kvA(
    const float* __restrict__ X, const float* __restrict__ qp,
    u16* __restrict__ dst)
{
    const int b = blockIdx.z, r0 = blockIdx.y * 64, l0 = blockIdx.x * 64;
    const int tid = threadIdx.x;
    __shared__ float ts[64][65];
    #pragma unroll
    for (int t = 0; t < 16; ++t) {
        int idx = t * 256 + tid;
        int ch = idx & 63, lr = idx >> 6;
        int lg = l0 + lr;
        float v = 0.f;
        if (lg < 2046) {
            if (r0 < 1024) v = X[(i64)lg * 4096 + b * 1024 + (r0 + ch)];
            else           v = qp[((i64)lg * 4 + b) * 512 + (r0 - 1024 + ch)];
        }
        ts[lr][ch] = v;
    }
    __syncthreads();
    #pragma unroll
    for (int t = 0; t < 16; ++t) {
        int idx = t * 256 + tid;
        int ll = idx & 63, rl = idx >> 6;
        dst[((i64)b * 1536 + r0 + rl) * 2048 + l0 + ll] = f2b(ts[ll][rl]);
    }
}

// ---------------------------------------------------------------------------
// Plain-bf16 MFMA GEMM: C[m][n] = sum_k A[m][k]*B[n][k]. 128x128 tile, BK=32,
// 4 waves (2x2 of 64x64). LDS XOR-swizzled ((r&3)<<4). Epilogue by MODE.
// ---------------------------------------------------------------------------
template<int MODE>
__global__ __launch_bounds__(256) void gemm_bf16(
    const u16* __restrict__ A, i64 a_bs,
    const u16* __restrict__ Bm,
    float* __restrict__ C, const float* __restrict__ bias,
    u16* __restrict__ x0, u16* __restrict__ x1,
    int Krow, int KT, int M_valid)
{
    __shared__ __align__(16) u16 As[4096], Bs[4096];   // 128 rows x 32 k each
    const int tid = threadIdx.x, lane = tid & 63, w = tid >> 6;
    const int fr = lane & 15, g = lane >> 4;
    const int nb = blockIdx.x, mb = blockIdx.y, bz = blockIdx.z;

    const u16* src = (w < 2)
        ? (A + (i64)bz * a_bs + ((i64)mb * 128 + (w & 1) * 64) * Krow)
        : (Bm + ((i64)nb * 128 + (w & 1) * 64) * Krow);
    u16* dstb = (w < 2) ? As : Bs;
    const int R0 = (w & 1) * 64;
    const int lr = lane >> 2, lcg = lane & 3;          // 16 rows x 4 chunks

    f32x4 acc[4][4];
    #pragma unroll
    for (int i = 0; i < 4; ++i)
        #pragma unroll
        for (int j = 0; j < 4; ++j)
            acc[i][j] = (f32x4){0.f, 0.f, 0.f, 0.f};

    u32x4 st[4];
    #pragma unroll
    for (int it = 0; it < 4; ++it)
        st[it] = *(const u32x4*)(src + (i64)(it * 16 + lr) * Krow + lcg * 8);

    const int wr = (w >> 1) * 64, wc = (w & 1) * 64;

    for (int kt = 0; kt < KT; ++kt) {
        __syncthreads();
        #pragma unroll
        for (int it = 0; it < 4; ++it) {
            int R = R0 + it * 16 + lr;
            *(u32x4*)((char*)dstb + R * 64 + ((lcg ^ (R & 3)) << 4)) = st[it];
        }
        __syncthreads();
        if (kt + 1 < KT) {
            #pragma unroll
            for (int it = 0; it < 4; ++it)
                st[it] = *(const u32x4*)(src + (i64)(it * 16 + lr) * Krow
                                             + (kt + 1) * 32 + lcg * 8);
        }
        bf16x8 ah[4], bh[4];
        #pragma unroll
        for (int mi = 0; mi < 4; ++mi) {
            int rr = wr + mi * 16 + fr;
            ah[mi] = *(const bf16x8*)((const char*)As + rr * 64 + ((g * 16) ^ ((rr & 3) << 4)));
        }
        #pragma unroll
        for (int ni = 0; ni < 4; ++ni) {
            int rr = wc + ni * 16 + fr;
            bh[ni] = *(const bf16x8*)((const char*)Bs + rr * 64 + ((g * 16) ^ ((rr & 3) << 4)));
        }
        #pragma unroll
        for (int mi = 0; mi < 4; ++mi)
            #pragma unroll
            for (int ni = 0; ni < 4; ++ni)
                acc[mi][ni] = __builtin_amdgcn_mfma_f32_16x16x32_bf16(
                    ah[mi], bh[ni], acc[mi][ni], 0, 0, 0);
    }

    #pragma unroll
    for (int mi = 0; mi < 4; ++mi)
        #pragma unroll
        for (int ni = 0; ni < 4; ++ni) {
            int gm0 = mb * 128 + wr + mi * 16 + g * 4;
            int gn  = nb * 128 + wc + ni * 16 + fr;
            #pragma unroll
            for (int r = 0; r < 4; ++r) {
                int gm = gm0 + r;
                float val = acc[mi][ni][r];
                if (MODE == 0) {
                    val += bias[gn];
                    C[(i64)gm * 512 + gn] = val;
                    x0[(i64)gm * 512 + gn] = f2b(val * QSCALE);
                } else if (MODE == 1) {
                    if (gm < 1024) {   // v: channel = e*16+h
                        int e = gm >> 4, hh = gm & 15;
                        i64 s = ((i64)(bz * 16 + hh) * 64 + e) * 1024
                              + (gn & ~63) + ((gn & 15) << 2) + ((gn >> 4) & 3);
                        x1[s] = f2b(val);
                    } else {           // k: channel-1024 = d*16+h
                        int c2 = gm - 1024, d = c2 >> 4, hh = c2 & 15;
                        x0[((i64)(bz * 16 + hh) * 1024 + gn) * 32 + d] = f2b(val);
                    }
                } else {
                    if (gm < M_valid)
                        C[(i64)bz * 1024 + (i64)gm * 4096 + gn] = val + bias[gn];
                }
            }
        }
}

// ---------------------------------------------------------------------------
// MFMA attention v4 = round-7 register pipeline + round-8 XCD affinity.
// Grid = 2048 1-D blocks; xcd = gid&7 owns bh in {xcd, xcd+8, ...}; 32
// consecutive same-XCD blocks share one bh -> K/V (192 KB) L2-resident.
// Block = 2 independent waves x 32 l-rows, NO barriers. Fully unrolled
// pipeline per tile t: V-loads(t) -> exp/pack/store P(t) -> QK(t+1) ->
// K-loads(t+2) -> PV(t). All global addresses are base + compile-time
// immediate after unroll; P LDS addresses are pt-invariant (hoisted).
// qb rows are l*4+b. kT: [(b h)][1024][32]; vT: [(b h)][64][1024] sigma(p).
// ---------------------------------------------------------------------------
__global__ __launch_bounds__(128) void attn_mfma(
    const u16* __restrict__ qb, const u16* __restrict__ kT,
    const u16* __restrict__ vT, u16* __restrict__ attA)
{
    const int g0 = blockIdx.x;
    const int xcd = g0 & 7, sub = g0 >> 3;
    const int lblk = sub & 31;                  // fastest: same bh 32x in a row
    const int bh = xcd + ((sub >> 5) << 3);     // 8 bh per XCD
    const int b = bh >> 4, h = bh & 15;
    const int tid = threadIdx.x, lane = tid & 63, w = tid >> 6;   // w in 0..1
    const int fr = lane & 15, g = lane >> 4;
    const int l0 = lblk * 64 + w * 32;

    __shared__ __align__(16) u16 ps_all[2][2048];     // 4 KB per wave
    char* psb = (char*)&ps_all[w][0];

    bf16x8 aq[2];
    #pragma unroll
    for (int mf = 0; mf < 2; ++mf)
        aq[mf] = *(const bf16x8*)(qb + ((i64)((l0 + mf * 16 + fr) * 4 + b) * 512
                                        + h * 32 + g * 8));   // row = l*4+b

    const u16* kbase = kT + (i64)bh * 32768;
    const u16* vbase = vT + (i64)bh * 65536;
    const f32x4 zf = {0.f, 0.f, 0.f, 0.f};

    float l_part[8] = {0.f, 0.f, 0.f, 0.f, 0.f, 0.f, 0.f, 0.f};
    f32x4 o[2][4];
    #pragma unroll
    for (int mf = 0; mf < 2; ++mf)
        #pragma unroll
        for (int nf = 0; nf < 4; ++nf)
            o[mf][nf] = zf;

    // prologue: K(0) -> QK(0) -> load K(1)
    bf16x8 kA[4];
    #pragma unroll
    for (int nf = 0; nf < 4; ++nf)
        kA[nf] = *(const bf16x8*)(kbase + (i64)(nf * 16 + fr) * 32 + g * 8);

    f32x4 s[2][4];
    #pragma unroll
    for (int nf = 0; nf < 4; ++nf) {
        s[0][nf] = __builtin_amdgcn_mfma_f32_16x16x32_bf16(aq[0], kA[nf], zf, 0, 0, 0);
        s[1][nf] = __builtin_amdgcn_mfma_f32_16x16x32_bf16(aq[1], kA[nf], zf, 0, 0, 0);
    }
    #pragma unroll
    for (int nf = 0; nf < 4; ++nf)
        kA[nf] = *(const bf16x8*)(kbase + (i64)(64 + nf * 16 + fr) * 32 + g * 8);

    const int pre0 = fr >> 1, pre1 = (fr & 1) * 8;

    #pragma unroll
    for (int pt = 0; pt < 16; ++pt) {
        const int p0 = pt * 64;

        // V(t) loads (L2-hit; latency covered by exp + QK below)
        bf16x8 vf[8];
        #pragma unroll
        for (int ks = 0; ks < 2; ++ks)
            #pragma unroll
            for (int nf = 0; nf < 4; ++nf)
                vf[ks * 4 + nf] = *(const bf16x8*)(vbase + (i64)(nf * 16 + fr) * 1024
                                                         + p0 + ks * 32 + g * 8);

        // exp + pack + LDS store P(t)  (consumes s)
        #pragma unroll
        for (int mf = 0; mf < 2; ++mf)
            #pragma unroll
            for (int r = 0; r < 4; ++r) {
                float p_[4];
                #pragma unroll
                for (int nf = 0; nf < 4; ++nf) p_[nf] = __builtin_exp2f(s[mf][nf][r]);
                l_part[mf * 4 + r] += (p_[0] + p_[1]) + (p_[2] + p_[3]);
                uint pk0 = cvt_pk_bf16(p_[0], p_[1]);
                uint pk1 = cvt_pk_bf16(p_[2], p_[3]);
                int ll = mf * 16 + g * 4 + r;
                int base = ll * 128 + ((pre0 ^ (ll & 7)) << 4) + pre1;
                *(uint*)(psb + base) = pk0;
                *(uint*)(psb + base + 4) = pk1;
            }

        // QK(t+1) into s (fills the LDS write->read gap)
        if (pt < 15) {
            #pragma unroll
            for (int nf = 0; nf < 4; ++nf) {
                s[0][nf] = __builtin_amdgcn_mfma_f32_16x16x32_bf16(aq[0], kA[nf], zf, 0, 0, 0);
                s[1][nf] = __builtin_amdgcn_mfma_f32_16x16x32_bf16(aq[1], kA[nf], zf, 0, 0, 0);
            }
        }
        // K(t+2) prefetch (kA free: QK(t+1) just consumed it)
        if (pt < 14) {
            #pragma unroll
            for (int nf = 0; nf < 4; ++nf)
                kA[nf] = *(const bf16x8*)(kbase + (i64)((pt + 2) * 64 + nf * 16 + fr) * 32
                                                + g * 8);
        }

        // PV(t)
        #pragma unroll
        for (int ks = 0; ks < 2; ++ks) {
            bf16x8 ap[2];
            #pragma unroll
            for (int mf = 0; mf < 2; ++mf) {
                int ll = mf * 16 + fr;
                ap[mf] = *(const bf16x8*)(psb + ll * 128 + ((((ks << 2) | g) ^ (ll & 7)) << 4));
            }
            #pragma unroll
            for (int nf = 0; nf < 4; ++nf) {
                o[0][nf] = __builtin_amdgcn_mfma_f32_16x16x32_bf16(ap[0], vf[ks * 4 + nf], o[0][nf], 0, 0, 0);
                o[1][nf] = __builtin_amdgcn_mfma_f32_16x16x32_bf16(ap[1], vf[ks * 4 + nf], o[1][nf], 0, 0, 0);
            }
        }
    }

    #pragma unroll
    for (int i = 0; i < 8; ++i) {
        float v = l_part[i];
        v += __shfl_xor(v, 1); v += __shfl_xor(v, 2);
        v += __shfl_xor(v, 4); v += __shfl_xor(v, 8);
        l_part[i] = 1.f / v;
    }
    #pragma unroll
    for (int mf = 0; mf < 2; ++mf)
        #pragma unroll
        for (int r = 0; r < 4; ++r) {
            int l = l0 + mf * 16 + g * 4 + r;
            if (l < 2046) {
                float inv = l_part[mf * 4 + r];
                #pragma unroll
                for (int nf = 0; nf < 4; ++nf)
                    attA[((i64)b * 2048 + l) * 1024 + h * 64 + nf * 16 + fr]
                        = f2b(o[mf][nf][r] * inv);
            }
        }
}

// ---------------------------------------------------------------------------
// launch
// ---------------------------------------------------------------------------
extern "C" void kernel_launch(void* const* d_in, const int* in_sizes, int n_in,
                              void* d_out, int out_size, void* d_ws, size_t ws_size,
                              hipStream_t stream) {
    const float* input = (const float*)d_in[0];  // [2046][4][1024]
    const float* w_kv  = (const float*)d_in[1];  // [1024][2048]
    const float* w_q   = (const float*)d_in[2];  // [512][1024]
    const float* b_q   = (const float*)d_in[3];  // [512]
    const float* w_out = (const float*)d_in[4];  // [1024][1024]
    const float* b_out = (const float*)d_in[5];  // [1024]
    float* out = (float*)d_out;                  // [2046][4][1024]

    char* W = (char*)d_ws;
    float* qp    = (float*)(W + 0);          // 8192x512 f32   (16 MB)
    u16* Xb      = (u16*)(W + 16777216);     // 8192x1024      (16 MB)
    u16* qb      = (u16*)(W + 33554432);     // 8192x512       (8 MB)
    u16* wq_b    = (u16*)(W + 41943040);     // 512x1024       (1 MB)
    u16* wkv_b   = (u16*)(W + 42991616);     // 1024x2048      (4 MB)
    u16* wout_b  = (u16*)(W + 47185920);     // 1024x1024      (2 MB)
    u16* kvA     = (u16*)(W + 49283072);     // 4x1536x2048    (24 MB)
    u16* kT      = (u16*)(W + 74448896);     // 4x16x1024x32   (4 MB)
    u16* vT      = (u16*)(W + 78643200);     // 4x16x64x1024   (8 MB)
    u16* attA    = (u16*)(W + 87031808);     // 4x2048x1024    (16 MB)

    dim3 blk(256);

    // bf16 conversions (independent)
    conv_pad<<<8192, blk, 0, stream>>>(input, Xb, 8184, 1024, 10, 1024);
    conv_pad<<<512,  blk, 0, stream>>>(w_q, wq_b, 512, 1024, 10, 1024);
    conv_pad<<<2048, blk, 0, stream>>>(w_kv, wkv_b, 1024, 2046, 11, 2048);
    conv_wout_perm<<<1024, blk, 0, stream>>>(w_out, wout_b);

    // q' = X @ w_q^T + b_q -> qp f32 + qb bf16(scaled)
    gemm_bf16<0><<<dim3(4, 64, 1), blk, 0, stream>>>(
        Xb, 0, wq_b, qp, b_q, qb, nullptr, 1024, 32, 8192);

    // combined kv A-panel (X + qp, transposed bf16)
    build_kvA<<<dim3(32, 24, 4), blk, 0, stream>>>(input, qp, kvA);

    // [v;k] = kvA @ wkv_b^T -> kT/vT bf16 (per b)
    gemm_bf16<1><<<dim3(8, 12, 4), blk, 0, stream>>>(
        kvA, (i64)1536 * 2048, wkv_b, nullptr, nullptr, kT, vT, 2048, 64, 1536);

    // attention -> attA bf16 (XCD-affine, barrier-free reg pipeline)
    attn_mfma<<<dim3(2048), dim3(128), 0, stream>>>(qb, kT, vT, attA);

    // out = attA @ wout_b^T + b_out (per b)
    gemm_bf16<2><<<dim3(8, 16, 4), blk, 0, stream>>>(
        attA, (i64)2048 * 1024, wout_b, out, b_out, nullptr, nullptr, 1024, 32, 2046);
}

// Round 10
// 228.280 us; speedup vs baseline: 1.0009x; 1.0009x over previous
//
#include <hip/hip_runtime.h>
#include <hip/hip_bf16.h>

typedef long long i64;
typedef unsigned int uint;
using u16 = unsigned short;
using f32x4  = __attribute__((ext_vector_type(4))) float;
using bf16x8 = __attribute__((ext_vector_type(8))) short;
using u32x4  = __attribute__((ext_vector_type(4))) uint;
using u16x4  = __attribute__((ext_vector_type(4))) u16;

// 0.125 (attention scaling) * log2(e): folded into q bf16 copy so softmax
// uses exp2 directly. Softmax is invariant to the base change.
#define QSCALE 0.18033688011112042f

__device__ __forceinline__ u16 f2b(float x) {   // f32 -> bf16 RNE
    uint u = __float_as_uint(x);
    return (u16)((u + 0x7FFFu + ((u >> 16) & 1u)) >> 16);
}
__device__ __forceinline__ uint cvt_pk_bf16(float lo, float hi) {
    uint r;
    asm("v_cvt_pk_bf16_f32 %0, %1, %2" : "=v"(r) : "v"(lo), "v"(hi));
    return r;
}

// ---------------------------------------------------------------------------
// conv_pad: f32 [M_valid x K_valid] (row stride s_row) -> bf16 [Mpad][Kpad],
// zero-padded. Kpad = 1<<kshift.
// ---------------------------------------------------------------------------
__global__ __launch_bounds__(256) void conv_pad(
    const float* __restrict__ src, u16* __restrict__ dst,
    int M_valid, int K_valid, int kshift, int s_row)
{
    i64 i = (i64)blockIdx.x * 256 + threadIdx.x;   // over Mpad*Kpad/4
    int m = (int)(i >> (kshift - 2));
    int k = ((int)(i & ((1 << (kshift - 2)) - 1))) << 2;
    u16x4 hv;
    #pragma unroll
    for (int j = 0; j < 4; ++j) {
        int kk = k + j;
        float x = (m < M_valid && kk < K_valid) ? src[(i64)m * s_row + kk] : 0.f;
        hv[j] = f2b(x);
    }
    *(u16x4*)(dst + ((i64)m << kshift) + k) = hv;
}

// ---------------------------------------------------------------------------
// conv_wout_perm: dst[n][kp] = bf16(w_out[n][(kp&63)*16 + (kp>>6)])
// ---------------------------------------------------------------------------
__global__ __launch_bounds__(256) void conv_wout_perm(
    const float* __restrict__ w, u16* __restrict__ dst)
{
    int i = blockIdx.x * 256 + threadIdx.x;        // over 1024*1024/4
    int n = i >> 8, kp4 = (i & 255) << 2;
    u16x4 hv;
    #pragma unroll
    for (int j = 0; j < 4; ++j) {
        int kp = kp4 + j;
        hv[j] = f2b(w[((i64)n << 10) + ((kp & 63) << 4) + (kp >> 6)]);
    }
    *(u16x4*)(dst + ((i64)n << 10) + kp4) = hv;
}

// ---------------------------------------------------------------------------
// build_kvA: A-panel for the kv-GEMM, transposed to l-contiguous bf16.
// rows 0..1023: A[d][l] = X[l][b][d]; rows 1024..1535: A[1024+c][l]=qp[(l4+b)c]
// ---------------------------------------------------------------------------
__global__ __launch_bounds__(256) void build_kvA(
    const float* __restrict__ X, const float* __restrict__ qp,
    u16* __restrict__ dst)
{
    const int b = blockIdx.z, r0 = blockIdx.y * 64, l0 = blockIdx.x * 64;
    const int tid = threadIdx.x;
    __shared__ float ts[64][65];
    #pragma unroll
    for (int t = 0; t < 16; ++t) {
        int idx = t * 256 + tid;
        int ch = idx & 63, lr = idx >> 6;
        int lg = l0 + lr;
        float v = 0.f;
        if (lg < 2046) {
            if (r0 < 1024) v = X[(i64)lg * 4096 + b * 1024 + (r0 + ch)];
            else           v = qp[((i64)lg * 4 + b) * 512 + (r0 - 1024 + ch)];
        }
        ts[lr][ch] = v;
    }
    __syncthreads();
    #pragma unroll
    for (int t = 0; t < 16; ++t) {
        int idx = t * 256 + tid;
        int ll = idx & 63, rl = idx >> 6;
        dst[((i64)b * 1536 + r0 + rl) * 2048 + l0 + ll] = f2b(ts[ll][rl]);
    }
}

// ---------------------------------------------------------------------------
// Plain-bf16 MFMA GEMM: C[m][n] = sum_k A[m][k]*B[n][k]. 128x128 tile, BK=32,
// 4 waves (2x2 of 64x64). LDS XOR-swizzled ((r&3)<<4). Epilogue by MODE.
// ---------------------------------------------------------------------------
template<int MODE>
__global__ __launch_bounds__(256) void gemm_bf16(
    const u16* __restrict__ A, i64 a_bs,
    const u16* __restrict__ Bm,
    float* __restrict__ C, const float* __restrict__ bias,
    u16* __restrict__ x0, u16* __restrict__ x1,
    int Krow, int KT, int M_valid)
{
    __shared__ __align__(16) u16 As[4096], Bs[4096];   // 128 rows x 32 k each
    const int tid = threadIdx.x, lane = tid & 63, w = tid >> 6;
    const int fr = lane & 15, g = lane >> 4;
    const int nb = blockIdx.x, mb = blockIdx.y, bz = blockIdx.z;

    const u16* src = (w < 2)
        ? (A + (i64)bz * a_bs + ((i64)mb * 128 + (w & 1) * 64) * Krow)
        : (Bm + ((i64)nb * 128 + (w & 1) * 64) * Krow);
    u16* dstb = (w < 2) ? As : Bs;
    const int R0 = (w & 1) * 64;
    const int lr = lane >> 2, lcg = lane & 3;          // 16 rows x 4 chunks

    f32x4 acc[4][4];
    #pragma unroll
    for (int i = 0; i < 4; ++i)
        #pragma unroll
        for (int j = 0; j < 4; ++j)
            acc[i][j] = (f32x4){0.f, 0.f, 0.f, 0.f};

    u32x4 st[4];
    #pragma unroll
    for (int it = 0; it < 4; ++it)
        st[it] = *(const u32x4*)(src + (i64)(it * 16 + lr) * Krow + lcg * 8);

    const int wr = (w >> 1) * 64, wc = (w & 1) * 64;

    for (int kt = 0; kt < KT; ++kt) {
        __syncthreads();
        #pragma unroll
        for (int it = 0; it < 4; ++it) {
            int R = R0 + it * 16 + lr;
            *(u32x4*)((char*)dstb + R * 64 + ((lcg ^ (R & 3)) << 4)) = st[it];
        }
        __syncthreads();
        if (kt + 1 < KT) {
            #pragma unroll
            for (int it = 0; it < 4; ++it)
                st[it] = *(const u32x4*)(src + (i64)(it * 16 + lr) * Krow
                                             + (kt + 1) * 32 + lcg * 8);
        }
        bf16x8 ah[4], bh[4];
        #pragma unroll
        for (int mi = 0; mi < 4; ++mi) {
            int rr = wr + mi * 16 + fr;
            ah[mi] = *(const bf16x8*)((const char*)As + rr * 64 + ((g * 16) ^ ((rr & 3) << 4)));
        }
        #pragma unroll
        for (int ni = 0; ni < 4; ++ni) {
            int rr = wc + ni * 16 + fr;
            bh[ni] = *(const bf16x8*)((const char*)Bs + rr * 64 + ((g * 16) ^ ((rr & 3) << 4)));
        }
        #pragma unroll
        for (int mi = 0; mi < 4; ++mi)
            #pragma unroll
            for (int ni = 0; ni < 4; ++ni)
                acc[mi][ni] = __builtin_amdgcn_mfma_f32_16x16x32_bf16(
                    ah[mi], bh[ni], acc[mi][ni], 0, 0, 0);
    }

    #pragma unroll
    for (int mi = 0; mi < 4; ++mi)
        #pragma unroll
        for (int ni = 0; ni < 4; ++ni) {
            int gm0 = mb * 128 + wr + mi * 16 + g * 4;
            int gn  = nb * 128 + wc + ni * 16 + fr;
            #pragma unroll
            for (int r = 0; r < 4; ++r) {
                int gm = gm0 + r;
                float val = acc[mi][ni][r];
                if (MODE == 0) {
                    val += bias[gn];
                    C[(i64)gm * 512 + gn] = val;
                    x0[(i64)gm * 512 + gn] = f2b(val * QSCALE);
                } else if (MODE == 1) {
                    if (gm < 1024) {   // v: channel = e*16+h
                        int e = gm >> 4, hh = gm & 15;
                        i64 s = ((i64)(bz * 16 + hh) * 64 + e) * 1024
                              + (gn & ~63) + ((gn & 15) << 2) + ((gn >> 4) & 3);
                        x1[s] = f2b(val);
                    } else {           // k: channel-1024 = d*16+h
                        int c2 = gm - 1024, d = c2 >> 4, hh = c2 & 15;
                        x0[((i64)(bz * 16 + hh) * 1024 + gn) * 32 + d] = f2b(val);
                    }
                } else {
                    if (gm < M_valid)
                        C[(i64)bz * 1024 + (i64)gm * 4096 + gn] = val + bias[gn];
                }
            }
        }
}

// ---------------------------------------------------------------------------
// MFMA attention v5: XCD-affine + barrier-free + P DOUBLE-BUFFER pipeline.
// Grid = 2048 1-D blocks; xcd = gid&7; 32 consecutive same-XCD blocks share
// one bh -> K/V (192 KB) L2-resident. Block = 2 independent waves x 32 rows.
// Iteration t (fully unrolled, t = 0..16):
//   V(t-1) loads -> exp/pack/store P(t, parity t&1) -> PV(t-1) (reads parity
//   (t-1)&1 -- written LAST iteration, no wait) -> QK(t+1) -> K(t+2) loads.
// The P(t) write->read gap now spans QK + K-loads + V-loads + next exp block.
// qb rows are l*4+b. kT: [(b h)][1024][32]; vT: [(b h)][64][1024] sigma(p).
// ---------------------------------------------------------------------------
__global__ __launch_bounds__(128) void attn_mfma(
    const u16* __restrict__ qb, const u16* __restrict__ kT,
    const u16* __restrict__ vT, u16* __restrict__ attA)
{
    const int g0 = blockIdx.x;
    const int xcd = g0 & 7, sub = g0 >> 3;
    const int lblk = sub & 31;                  // fastest: same bh 32x in a row
    const int bh = xcd + ((sub >> 5) << 3);     // 8 bh per XCD
    const int b = bh >> 4, h = bh & 15;
    const int tid = threadIdx.x, lane = tid & 63, w = tid >> 6;   // w in 0..1
    const int fr = lane & 15, g = lane >> 4;
    const int l0 = lblk * 64 + w * 32;

    __shared__ __align__(16) u16 ps_all[2][2][2048];   // [wave][parity], 4 KB each
    char* psw0 = (char*)&ps_all[w][0][0];
    char* psw1 = (char*)&ps_all[w][1][0];

    bf16x8 aq[2];
    #pragma unroll
    for (int mf = 0; mf < 2; ++mf)
        aq[mf] = *(const bf16x8*)(qb + ((i64)((l0 + mf * 16 + fr) * 4 + b) * 512
                                        + h * 32 + g * 8));   // row = l*4+b

    const u16* kbase = kT + (i64)bh * 32768;
    const u16* vbase = vT + (i64)bh * 65536;
    const f32x4 zf = {0.f, 0.f, 0.f, 0.f};

    float l_part[8] = {0.f, 0.f, 0.f, 0.f, 0.f, 0.f, 0.f, 0.f};
    f32x4 o[2][4];
    #pragma unroll
    for (int mf = 0; mf < 2; ++mf)
        #pragma unroll
        for (int nf = 0; nf < 4; ++nf)
            o[mf][nf] = zf;

    // prologue: K(0) -> QK(0) -> load K(1)
    bf16x8 kA[4];
    #pragma unroll
    for (int nf = 0; nf < 4; ++nf)
        kA[nf] = *(const bf16x8*)(kbase + (i64)(nf * 16 + fr) * 32 + g * 8);

    f32x4 s[2][4];
    #pragma unroll
    for (int nf = 0; nf < 4; ++nf) {
        s[0][nf] = __builtin_amdgcn_mfma_f32_16x16x32_bf16(aq[0], kA[nf], zf, 0, 0, 0);
        s[1][nf] = __builtin_amdgcn_mfma_f32_16x16x32_bf16(aq[1], kA[nf], zf, 0, 0, 0);
    }
    #pragma unroll
    for (int nf = 0; nf < 4; ++nf)
        kA[nf] = *(const bf16x8*)(kbase + (i64)(64 + nf * 16 + fr) * 32 + g * 8);

    const int pre0 = fr >> 1, pre1 = (fr & 1) * 8;

    #pragma unroll
    for (int t = 0; t <= 16; ++t) {
        // 1. V(t-1) loads (L2-hit; consumed by PV below, covered by exp block)
        bf16x8 vf[8];
        if (t > 0) {
            const int pv = (t - 1) * 64;
            #pragma unroll
            for (int ks = 0; ks < 2; ++ks)
                #pragma unroll
                for (int nf = 0; nf < 4; ++nf)
                    vf[ks * 4 + nf] = *(const bf16x8*)(vbase + (i64)(nf * 16 + fr) * 1024
                                                             + pv + ks * 32 + g * 8);
        }

        // 2. exp + pack + LDS store P(t) into parity t&1 (consumes s(t))
        if (t < 16) {
            char* psw = (t & 1) ? psw1 : psw0;
            #pragma unroll
            for (int mf = 0; mf < 2; ++mf)
                #pragma unroll
                for (int r = 0; r < 4; ++r) {
                    float p_[4];
                    #pragma unroll
                    for (int nf = 0; nf < 4; ++nf) p_[nf] = __builtin_exp2f(s[mf][nf][r]);
                    l_part[mf * 4 + r] += (p_[0] + p_[1]) + (p_[2] + p_[3]);
                    uint pk0 = cvt_pk_bf16(p_[0], p_[1]);
                    uint pk1 = cvt_pk_bf16(p_[2], p_[3]);
                    int ll = mf * 16 + g * 4 + r;
                    int base = ll * 128 + ((pre0 ^ (ll & 7)) << 4) + pre1;
                    *(uint*)(psw + base) = pk0;
                    *(uint*)(psw + base + 4) = pk1;
                }
        }

        // 3. PV(t-1): reads parity (t-1)&1 (written last iteration -- retired)
        if (t > 0) {
            const char* psr = ((t - 1) & 1) ? psw1 : psw0;
            #pragma unroll
            for (int ks = 0; ks < 2; ++ks) {
                bf16x8 ap[2];
                #pragma unroll
                for (int mf = 0; mf < 2; ++mf) {
                    int ll = mf * 16 + fr;
                    ap[mf] = *(const bf16x8*)(psr + ll * 128 + ((((ks << 2) | g) ^ (ll & 7)) << 4));
                }
                #pragma unroll
                for (int nf = 0; nf < 4; ++nf) {
                    o[0][nf] = __builtin_amdgcn_mfma_f32_16x16x32_bf16(ap[0], vf[ks * 4 + nf], o[0][nf], 0, 0, 0);
                    o[1][nf] = __builtin_amdgcn_mfma_f32_16x16x32_bf16(ap[1], vf[ks * 4 + nf], o[1][nf], 0, 0, 0);
                }
            }
        }

        // 4. QK(t+1) into s (uses kA = K(t+1), loaded last iteration)
        if (t + 1 < 16) {
            #pragma unroll
            for (int nf = 0; nf < 4; ++nf) {
                s[0][nf] = __builtin_amdgcn_mfma_f32_16x16x32_bf16(aq[0], kA[nf], zf, 0, 0, 0);
                s[1][nf] = __builtin_amdgcn_mfma_f32_16x16x32_bf16(aq[1], kA[nf], zf, 0, 0, 0);
            }
        }

        // 5. K(t+2) prefetch (kA free: QK(t+1) just consumed it)
        if (t + 2 < 16) {
            #pragma unroll
            for (int nf = 0; nf < 4; ++nf)
                kA[nf] = *(const bf16x8*)(kbase + (i64)((t + 2) * 64 + nf * 16 + fr) * 32
                                                + g * 8);
        }
    }

    #pragma unroll
    for (int i = 0; i < 8; ++i) {
        float v = l_part[i];
        v += __shfl_xor(v, 1); v += __shfl_xor(v, 2);
        v += __shfl_xor(v, 4); v += __shfl_xor(v, 8);
        l_part[i] = 1.f / v;
    }
    #pragma unroll
    for (int mf = 0; mf < 2; ++mf)
        #pragma unroll
        for (int r = 0; r < 4; ++r) {
            int l = l0 + mf * 16 + g * 4 + r;
            if (l < 2046) {
                float inv = l_part[mf * 4 + r];
                #pragma unroll
                for (int nf = 0; nf < 4; ++nf)
                    attA[((i64)b * 2048 + l) * 1024 + h * 64 + nf * 16 + fr]
                        = f2b(o[mf][nf][r] * inv);
            }
        }
}

// ---------------------------------------------------------------------------
// launch
// ---------------------------------------------------------------------------
extern "C" void kernel_launch(void* const* d_in, const int* in_sizes, int n_in,
                              void* d_out, int out_size, void* d_ws, size_t ws_size,
                              hipStream_t stream) {
    const float* input = (const float*)d_in[0];  // [2046][4][1024]
    const float* w_kv  = (const float*)d_in[1];  // [1024][2048]
    const float* w_q   = (const float*)d_in[2];  // [512][1024]
    const float* b_q   = (const float*)d_in[3];  // [512]
    const float* w_out = (const float*)d_in[4];  // [1024][1024]
    const float* b_out = (const float*)d_in[5];  // [1024]
    float* out = (float*)d_out;                  // [2046][4][1024]

    char* W = (char*)d_ws;
    float* qp    = (float*)(W + 0);          // 8192x512 f32   (16 MB)
    u16* Xb      = (u16*)(W + 16777216);     // 8192x1024      (16 MB)
    u16* qb      = (u16*)(W + 33554432);     // 8192x512       (8 MB)
    u16* wq_b    = (u16*)(W + 41943040);     // 512x1024       (1 MB)
    u16* wkv_b   = (u16*)(W + 42991616);     // 1024x2048      (4 MB)
    u16* wout_b  = (u16*)(W + 47185920);     // 1024x1024      (2 MB)
    u16* kvA     = (u16*)(W + 49283072);     // 4x1536x2048    (24 MB)
    u16* kT      = (u16*)(W + 74448896);     // 4x16x1024x32   (4 MB)
    u16* vT      = (u16*)(W + 78643200);     // 4x16x64x1024   (8 MB)
    u16* attA    = (u16*)(W + 87031808);     // 4x2048x1024    (16 MB)

    dim3 blk(256);

    // bf16 conversions (independent)
    conv_pad<<<8192, blk, 0, stream>>>(input, Xb, 8184, 1024, 10, 1024);
    conv_pad<<<512,  blk, 0, stream>>>(w_q, wq_b, 512, 1024, 10, 1024);
    conv_pad<<<2048, blk, 0, stream>>>(w_kv, wkv_b, 1024, 2046, 11, 2048);
    conv_wout_perm<<<1024, blk, 0, stream>>>(w_out, wout_b);

    // q' = X @ w_q^T + b_q -> qp f32 + qb bf16(scaled)
    gemm_bf16<0><<<dim3(4, 64, 1), blk, 0, stream>>>(
        Xb, 0, wq_b, qp, b_q, qb, nullptr, 1024, 32, 8192);

    // combined kv A-panel (X + qp, transposed bf16)
    build_kvA<<<dim3(32, 24, 4), blk, 0, stream>>>(input, qp, kvA);

    // [v;k] = kvA @ wkv_b^T -> kT/vT bf16 (per b)
    gemm_bf16<1><<<dim3(8, 12, 4), blk, 0, stream>>>(
        kvA, (i64)1536 * 2048, wkv_b, nullptr, nullptr, kT, vT, 2048, 64, 1536);

    // attention -> attA bf16 (XCD-affine, P-double-buffered pipeline)
    attn_mfma<<<dim3(2048), dim3(128), 0, stream>>>(qb, kT, vT, attA);

    // out = attA @ wout_b^T + b_out (per b)
    gemm_bf16<2><<<dim3(8, 16, 4), blk, 0, stream>>>(
        attA, (i64)2048 * 1024, wout_b, out, b_out, nullptr, nullptr, 1024, 32, 2046);
}

// Round 11
// 205.532 us; speedup vs baseline: 1.1117x; 1.1107x over previous
//
#include <hip/hip_runtime.h>
#include <hip/hip_bf16.h>

typedef long long i64;
typedef unsigned int uint;
using u16 = unsigned short;
using f32x4  = __attribute__((ext_vector_type(4))) float;
using bf16x8 = __attribute__((ext_vector_type(8))) short;
using u32x4  = __attribute__((ext_vector_type(4))) uint;
using u16x4  = __attribute__((ext_vector_type(4))) u16;

// 0.125 (attention scaling) * log2(e): folded into q bf16 copy so softmax
// uses exp2 directly. Softmax is invariant to the base change.
#define QSCALE 0.18033688011112042f

__device__ __forceinline__ u16 f2b(float x) {   // f32 -> bf16 RNE
    uint u = __float_as_uint(x);
    return (u16)((u + 0x7FFFu + ((u >> 16) & 1u)) >> 16);
}
__device__ __forceinline__ uint cvt_pk_bf16(float lo, float hi) {
    uint r;
    asm("v_cvt_pk_bf16_f32 %0, %1, %2" : "=v"(r) : "v"(lo), "v"(hi));
    return r;
}

// ---------------------------------------------------------------------------
// conv_pad: f32 [M_valid x K_valid] (row stride s_row) -> bf16 [Mpad][Kpad],
// zero-padded. Kpad = 1<<kshift.
// ---------------------------------------------------------------------------
__global__ __launch_bounds__(256) void conv_pad(
    const float* __restrict__ src, u16* __restrict__ dst,
    int M_valid, int K_valid, int kshift, int s_row)
{
    i64 i = (i64)blockIdx.x * 256 + threadIdx.x;   // over Mpad*Kpad/4
    int m = (int)(i >> (kshift - 2));
    int k = ((int)(i & ((1 << (kshift - 2)) - 1))) << 2;
    u16x4 hv;
    #pragma unroll
    for (int j = 0; j < 4; ++j) {
        int kk = k + j;
        float x = (m < M_valid && kk < K_valid) ? src[(i64)m * s_row + kk] : 0.f;
        hv[j] = f2b(x);
    }
    *(u16x4*)(dst + ((i64)m << kshift) + k) = hv;
}

// ---------------------------------------------------------------------------
// conv_wout_perm: dst[n][kp] = bf16(w_out[n][(kp&63)*16 + (kp>>6)])
// ---------------------------------------------------------------------------
__global__ __launch_bounds__(256) void conv_wout_perm(
    const float* __restrict__ w, u16* __restrict__ dst)
{
    int i = blockIdx.x * 256 + threadIdx.x;        // over 1024*1024/4
    int n = i >> 8, kp4 = (i & 255) << 2;
    u16x4 hv;
    #pragma unroll
    for (int j = 0; j < 4; ++j) {
        int kp = kp4 + j;
        hv[j] = f2b(w[((i64)n << 10) + ((kp & 63) << 4) + (kp >> 6)]);
    }
    *(u16x4*)(dst + ((i64)n << 10) + kp4) = hv;
}

// ---------------------------------------------------------------------------
// build_kvA: A-panel for the kv-GEMM, transposed to l-contiguous bf16.
// rows 0..1023: A[d][l] = X[l][b][d]; rows 1024..1535: A[1024+c][l]=qp[(l4+b)c]
// ---------------------------------------------------------------------------
__global__ __launch_bounds__(256) void build_kvA(
    const float* __restrict__ X, const float* __restrict__ qp,
    u16* __restrict__ dst)
{
    const int b = blockIdx.z, r0 = blockIdx.y * 64, l0 = blockIdx.x * 64;
    const int tid = threadIdx.x;
    __shared__ float ts[64][65];
    #pragma unroll
    for (int t = 0; t < 16; ++t) {
        int idx = t * 256 + tid;
        int ch = idx & 63, lr = idx >> 6;
        int lg = l0 + lr;
        float v = 0.f;
        if (lg < 2046) {
            if (r0 < 1024) v = X[(i64)lg * 4096 + b * 1024 + (r0 + ch)];
            else           v = qp[((i64)lg * 4 + b) * 512 + (r0 - 1024 + ch)];
        }
        ts[lr][ch] = v;
    }
    __syncthreads();
    #pragma unroll
    for (int t = 0; t < 16; ++t) {
        int idx = t * 256 + tid;
        int ll = idx & 63, rl = idx >> 6;
        dst[((i64)b * 1536 + r0 + rl) * 2048 + l0 + ll] = f2b(ts[ll][rl]);
    }
}

// ---------------------------------------------------------------------------
// Plain-bf16 MFMA GEMM: C[m][n] = sum_k A[m][k]*B[n][k]. 128x128 tile, BK=32,
// 4 waves (2x2 of 64x64). LDS XOR-swizzled ((r&3)<<4). Epilogue by MODE.
// ---------------------------------------------------------------------------
template<int MODE>
__global__ __launch_bounds__(256) void gemm_bf16(
    const u16* __restrict__ A, i64 a_bs,
    const u16* __restrict__ Bm,
    float* __restrict__ C, const float* __restrict__ bias,
    u16* __restrict__ x0, u16* __restrict__ x1,
    int Krow, int KT, int M_valid)
{
    __shared__ __align__(16) u16 As[4096], Bs[4096];   // 128 rows x 32 k each
    const int tid = threadIdx.x, lane = tid & 63, w = tid >> 6;
    const int fr = lane & 15, g = lane >> 4;
    const int nb = blockIdx.x, mb = blockIdx.y, bz = blockIdx.z;

    const u16* src = (w < 2)
        ? (A + (i64)bz * a_bs + ((i64)mb * 128 + (w & 1) * 64) * Krow)
        : (Bm + ((i64)nb * 128 + (w & 1) * 64) * Krow);
    u16* dstb = (w < 2) ? As : Bs;
    const int R0 = (w & 1) * 64;
    const int lr = lane >> 2, lcg = lane & 3;          // 16 rows x 4 chunks

    f32x4 acc[4][4];
    #pragma unroll
    for (int i = 0; i < 4; ++i)
        #pragma unroll
        for (int j = 0; j < 4; ++j)
            acc[i][j] = (f32x4){0.f, 0.f, 0.f, 0.f};

    u32x4 st[4];
    #pragma unroll
    for (int it = 0; it < 4; ++it)
        st[it] = *(const u32x4*)(src + (i64)(it * 16 + lr) * Krow + lcg * 8);

    const int wr = (w >> 1) * 64, wc = (w & 1) * 64;

    for (int kt = 0; kt < KT; ++kt) {
        __syncthreads();
        #pragma unroll
        for (int it = 0; it < 4; ++it) {
            int R = R0 + it * 16 + lr;
            *(u32x4*)((char*)dstb + R * 64 + ((lcg ^ (R & 3)) << 4)) = st[it];
        }
        __syncthreads();
        if (kt + 1 < KT) {
            #pragma unroll
            for (int it = 0; it < 4; ++it)
                st[it] = *(const u32x4*)(src + (i64)(it * 16 + lr) * Krow
                                             + (kt + 1) * 32 + lcg * 8);
        }
        bf16x8 ah[4], bh[4];
        #pragma unroll
        for (int mi = 0; mi < 4; ++mi) {
            int rr = wr + mi * 16 + fr;
            ah[mi] = *(const bf16x8*)((const char*)As + rr * 64 + ((g * 16) ^ ((rr & 3) << 4)));
        }
        #pragma unroll
        for (int ni = 0; ni < 4; ++ni) {
            int rr = wc + ni * 16 + fr;
            bh[ni] = *(const bf16x8*)((const char*)Bs + rr * 64 + ((g * 16) ^ ((rr & 3) << 4)));
        }
        #pragma unroll
        for (int mi = 0; mi < 4; ++mi)
            #pragma unroll
            for (int ni = 0; ni < 4; ++ni)
                acc[mi][ni] = __builtin_amdgcn_mfma_f32_16x16x32_bf16(
                    ah[mi], bh[ni], acc[mi][ni], 0, 0, 0);
    }

    #pragma unroll
    for (int mi = 0; mi < 4; ++mi)
        #pragma unroll
        for (int ni = 0; ni < 4; ++ni) {
            int gm0 = mb * 128 + wr + mi * 16 + g * 4;
            int gn  = nb * 128 + wc + ni * 16 + fr;
            #pragma unroll
            for (int r = 0; r < 4; ++r) {
                int gm = gm0 + r;
                float val = acc[mi][ni][r];
                if (MODE == 0) {
                    val += bias[gn];
                    C[(i64)gm * 512 + gn] = val;
                    x0[(i64)gm * 512 + gn] = f2b(val * QSCALE);
                } else if (MODE == 1) {
                    if (gm < 1024) {   // v: channel = e*16+h
                        int e = gm >> 4, hh = gm & 15;
                        i64 s = ((i64)(bz * 16 + hh) * 64 + e) * 1024
                              + (gn & ~63) + ((gn & 15) << 2) + ((gn >> 4) & 3);
                        x1[s] = f2b(val);
                    } else {           // k: channel-1024 = d*16+h
                        int c2 = gm - 1024, d = c2 >> 4, hh = c2 & 15;
                        x0[((i64)(bz * 16 + hh) * 1024 + gn) * 32 + d] = f2b(val);
                    }
                } else {
                    if (gm < M_valid)
                        C[(i64)bz * 1024 + (i64)gm * 4096 + gn] = val + bias[gn];
                }
            }
        }
}

// ---------------------------------------------------------------------------
// MFMA attention v6: 4-wave blocks + XCD affinity + K AND V cooperatively
// staged in LDS (double-buffered, ONE barrier/iter) + full unroll.
// Grid = 1024 1-D blocks; xcd = gid&7; 16 consecutive same-XCD blocks share
// one bh (K/V L2-resident). Block = 4 waves x 32 l-rows = 128 rows.
// Per iter t: issue 3x16B global loads for tile t+1 -> QK(t) from LDS K ->
// exp/pack/store P(t) -> ds_write tile t+1 into other buffer -> PV(t) from
// LDS V + P -> barrier.
// LDS conflict design: K pitch 80B (2-way, free). V written LINEARLY
// (conflict-free) with a pre-swizzled global source chunk c = s ^ (row&7);
// reads use slot = (ks*4+g) ^ (row&7) -> 2-way (free). P as before.
// qb rows l*4+b; kT [(bh)][1024][32]; vT [(bh)][64][1024] sigma(p).
// ---------------------------------------------------------------------------
__global__ __launch_bounds__(256) void attn_mfma(
    const u16* __restrict__ qb, const u16* __restrict__ kT,
    const u16* __restrict__ vT, u16* __restrict__ attA)
{
    const int g0 = blockIdx.x;
    const int xcd = g0 & 7, sub = g0 >> 3;
    const int lblk = sub & 15;                  // same bh for 16 consecutive
    const int bh = xcd + ((sub >> 4) << 3);     // 8 bh per XCD
    const int b = bh >> 4, h = bh & 15;
    const int tid = threadIdx.x, lane = tid & 63, w = tid >> 6;   // 0..3
    const int fr = lane & 15, g = lane >> 4;
    const int l0 = lblk * 128 + w * 32;

    __shared__ __align__(16) u16 kbuf[2][2560];    // 64 rows x 40 u16 (80B pitch)
    __shared__ __align__(16) u16 vbuf[2][4096];    // 64 rows x 64 u16 (128B, swz)
    __shared__ __align__(16) u16 ps_all[4][2048];  // P: 4KB per wave
    char* psb = (char*)&ps_all[w][0];

    bf16x8 aq[2];
    #pragma unroll
    for (int mf = 0; mf < 2; ++mf)
        aq[mf] = *(const bf16x8*)(qb + ((i64)((l0 + mf * 16 + fr) * 4 + b) * 512
                                        + h * 32 + g * 8));   // row = l*4+b

    const f32x4 zf = {0.f, 0.f, 0.f, 0.f};

    // staging constants
    const int kr = tid >> 2, kc = tid & 3;              // K: row 0..63, chunk 0..3
    const u16* ksrc = kT + (i64)bh * 32768 + kr * 32 + kc * 8;        // + t*2048
    char* kdst = (char*)&kbuf[0][0] + kr * 80 + kc * 16;              // + buf*5120
    const int vr0 = tid >> 3, s0 = tid & 7;             // V: rows vr0, vr0+32
    const int c0 = s0 ^ (vr0 & 7);                      // pre-swizzled src chunk
    const u16* vsrc = vT + (i64)bh * 65536 + vr0 * 1024 + c0 * 8;     // + t*64
    char* vdst0 = (char*)&vbuf[0][0] + vr0 * 128 + s0 * 16;           // + buf*8192
    // row vr0+32: (vr0+32)&7 == vr0&7 -> same chunk c0, source +32*1024
    float l_part[8] = {0.f, 0.f, 0.f, 0.f, 0.f, 0.f, 0.f, 0.f};
    f32x4 o[2][4];
    #pragma unroll
    for (int mf = 0; mf < 2; ++mf)
        #pragma unroll
        for (int nf = 0; nf < 4; ++nf)
            o[mf][nf] = zf;

    // prologue: stage tile 0 into buffer 0
    {
        u32x4 k0 = *(const u32x4*)(ksrc);
        u32x4 v0 = *(const u32x4*)(vsrc);
        u32x4 v1 = *(const u32x4*)(vsrc + 32 * 1024);
        *(u32x4*)(kdst) = k0;
        *(u32x4*)(vdst0) = v0;
        *(u32x4*)(vdst0 + 32 * 128) = v1;
    }
    __syncthreads();

    const int pre0 = fr >> 1, pre1 = (fr & 1) * 8;

    #pragma unroll
    for (int t = 0; t < 16; ++t) {
        const int cur = t & 1;

        // 1. issue global loads for tile t+1 (consumed by ds_write below)
        u32x4 knx, vnx0, vnx1;
        if (t < 15) {
            knx  = *(const u32x4*)(ksrc + (t + 1) * 2048);
            vnx0 = *(const u32x4*)(vsrc + (t + 1) * 64);
            vnx1 = *(const u32x4*)(vsrc + 32 * 1024 + (t + 1) * 64);
        }

        // 2. QK(t) from LDS K
        const char* kc_ = (const char*)&kbuf[cur][0];
        f32x4 s[2][4];
        #pragma unroll
        for (int nf = 0; nf < 4; ++nf) {
            bf16x8 bk = *(const bf16x8*)(kc_ + (nf * 16 + fr) * 80 + g * 16);
            s[0][nf] = __builtin_amdgcn_mfma_f32_16x16x32_bf16(aq[0], bk, zf, 0, 0, 0);
            s[1][nf] = __builtin_amdgcn_mfma_f32_16x16x32_bf16(aq[1], bk, zf, 0, 0, 0);
        }

        // 3. exp + pack + LDS store P(t) (wave-private)
        #pragma unroll
        for (int mf = 0; mf < 2; ++mf)
            #pragma unroll
            for (int r = 0; r < 4; ++r) {
                float p_[4];
                #pragma unroll
                for (int nf = 0; nf < 4; ++nf) p_[nf] = __builtin_exp2f(s[mf][nf][r]);
                l_part[mf * 4 + r] += (p_[0] + p_[1]) + (p_[2] + p_[3]);
                uint pk0 = cvt_pk_bf16(p_[0], p_[1]);
                uint pk1 = cvt_pk_bf16(p_[2], p_[3]);
                int ll = mf * 16 + g * 4 + r;
                int base = ll * 128 + ((pre0 ^ (ll & 7)) << 4) + pre1;
                *(uint*)(psb + base) = pk0;
                *(uint*)(psb + base + 4) = pk1;
            }

        // 4. write staged tile t+1 into the other buffer (vmcnt covered by 2+3)
        if (t < 15) {
            const int nb_ = cur ^ 1;
            *(u32x4*)(kdst + nb_ * 5120) = knx;
            *(u32x4*)(vdst0 + nb_ * 8192) = vnx0;
            *(u32x4*)(vdst0 + nb_ * 8192 + 32 * 128) = vnx1;
        }

        // 5. PV(t) from LDS V + P
        const char* vc_ = (const char*)&vbuf[cur][0];
        #pragma unroll
        for (int ks = 0; ks < 2; ++ks) {
            bf16x8 ap[2];
            #pragma unroll
            for (int mf = 0; mf < 2; ++mf) {
                int ll = mf * 16 + fr;
                ap[mf] = *(const bf16x8*)(psb + ll * 128 + ((((ks << 2) | g) ^ (ll & 7)) << 4));
            }
            #pragma unroll
            for (int nf = 0; nf < 4; ++nf) {
                int row = nf * 16 + fr;
                int slot = ((ks << 2) | g) ^ (row & 7);
                bf16x8 bv = *(const bf16x8*)(vc_ + row * 128 + slot * 16);
                o[0][nf] = __builtin_amdgcn_mfma_f32_16x16x32_bf16(ap[0], bv, o[0][nf], 0, 0, 0);
                o[1][nf] = __builtin_amdgcn_mfma_f32_16x16x32_bf16(ap[1], bv, o[1][nf], 0, 0, 0);
            }
        }

        __syncthreads();   // buf[cur] reads done; buf[cur^1] writes visible
    }

    #pragma unroll
    for (int i = 0; i < 8; ++i) {
        float v = l_part[i];
        v += __shfl_xor(v, 1); v += __shfl_xor(v, 2);
        v += __shfl_xor(v, 4); v += __shfl_xor(v, 8);
        l_part[i] = 1.f / v;
    }
    #pragma unroll
    for (int mf = 0; mf < 2; ++mf)
        #pragma unroll
        for (int r = 0; r < 4; ++r) {
            int l = l0 + mf * 16 + g * 4 + r;
            if (l < 2046) {
                float inv = l_part[mf * 4 + r];
                #pragma unroll
                for (int nf = 0; nf < 4; ++nf)
                    attA[((i64)b * 2048 + l) * 1024 + h * 64 + nf * 16 + fr]
                        = f2b(o[mf][nf][r] * inv);
            }
        }
}

// ---------------------------------------------------------------------------
// launch
// ---------------------------------------------------------------------------
extern "C" void kernel_launch(void* const* d_in, const int* in_sizes, int n_in,
                              void* d_out, int out_size, void* d_ws, size_t ws_size,
                              hipStream_t stream) {
    const float* input = (const float*)d_in[0];  // [2046][4][1024]
    const float* w_kv  = (const float*)d_in[1];  // [1024][2048]
    const float* w_q   = (const float*)d_in[2];  // [512][1024]
    const float* b_q   = (const float*)d_in[3];  // [512]
    const float* w_out = (const float*)d_in[4];  // [1024][1024]
    const float* b_out = (const float*)d_in[5];  // [1024]
    float* out = (float*)d_out;                  // [2046][4][1024]

    char* W = (char*)d_ws;
    float* qp    = (float*)(W + 0);          // 8192x512 f32   (16 MB)
    u16* Xb      = (u16*)(W + 16777216);     // 8192x1024      (16 MB)
    u16* qb      = (u16*)(W + 33554432);     // 8192x512       (8 MB)
    u16* wq_b    = (u16*)(W + 41943040);     // 512x1024       (1 MB)
    u16* wkv_b   = (u16*)(W + 42991616);     // 1024x2048      (4 MB)
    u16* wout_b  = (u16*)(W + 47185920);     // 1024x1024      (2 MB)
    u16* kvA     = (u16*)(W + 49283072);     // 4x1536x2048    (24 MB)
    u16* kT      = (u16*)(W + 74448896);     // 4x16x1024x32   (4 MB)
    u16* vT      = (u16*)(W + 78643200);     // 4x16x64x1024   (8 MB)
    u16* attA    = (u16*)(W + 87031808);     // 4x2048x1024    (16 MB)

    dim3 blk(256);

    // bf16 conversions (independent)
    conv_pad<<<8192, blk, 0, stream>>>(input, Xb, 8184, 1024, 10, 1024);
    conv_pad<<<512,  blk, 0, stream>>>(w_q, wq_b, 512, 1024, 10, 1024);
    conv_pad<<<2048, blk, 0, stream>>>(w_kv, wkv_b, 1024, 2046, 11, 2048);
    conv_wout_perm<<<1024, blk, 0, stream>>>(w_out, wout_b);

    // q' = X @ w_q^T + b_q -> qp f32 + qb bf16(scaled)
    gemm_bf16<0><<<dim3(4, 64, 1), blk, 0, stream>>>(
        Xb, 0, wq_b, qp, b_q, qb, nullptr, 1024, 32, 8192);

    // combined kv A-panel (X + qp, transposed bf16)
    build_kvA<<<dim3(32, 24, 4), blk, 0, stream>>>(input, qp, kvA);

    // [v;k] = kvA @ wkv_b^T -> kT/vT bf16 (per b)
    gemm_bf16<1><<<dim3(8, 12, 4), blk, 0, stream>>>(
        kvA, (i64)1536 * 2048, wkv_b, nullptr, nullptr, kT, vT, 2048, 64, 1536);

    // attention -> attA bf16 (4-wave, staged K+V, XCD-affine, unrolled)
    attn_mfma<<<dim3(1024), blk, 0, stream>>>(qb, kT, vT, attA);

    // out = attA @ wout_b^T + b_out (per b)
    gemm_bf16<2><<<dim3(8, 16, 4), blk, 0, stream>>>(
        attA, (i64)2048 * 1024, wout_b, out, b_out, nullptr, nullptr, 1024, 32, 2046);
}